// Round 7
// baseline (127.871 us; speedup 1.0000x reference)
//
#include <hip/hip_runtime.h>

// Problem constants: B=1, T=5, C=64, H=W=32, F=10
#define N_TOK   5120      // T*H*W
#define C_IN    64
#define F_OUT   10
#define FP      12        // padded row stride: [0..9]=data, [10..11]=pad

#define NCHUNKS 128       // denom n-chunks  -> grid 20*128 = 2560 blocks
#define MCHUNKS 128       // main  m-chunks  -> grid 20*128 = 2560 blocks

// R4 lesson: grid-wide single-counter barriers cost ~250 us on 8 XCDs; stay
// multi-kernel. R6 lesson: atomic write-through traffic (13-26 MB) is NOT
// binding; occupancy is. R7 change: K/V/Q tile rows are read at WAVE-UNIFORM
// addresses (loop counter + blockIdx only) -> serve them via scalar loads
// (SGPR operands) instead of LDS staging. Removes the LDS pipe cost,
// staging stores, and both __syncthreads per tile from the O(N^2) loops.

// ---------------------------------------------------------------------------
// Kernel A: q/k/v pointwise conv. Thread = one (n, f, arr) output value.
// 600 blocks: arr(3) x f(10) x nblk(20). 64 coalesced loads + 64 FMA each.
// Prologue: blocks [0,200) zero out (51200 f), blocks [200,220) zero dsum.
// ---------------------------------------------------------------------------
__global__ __launch_bounds__(256) void qkv_kernel(
    const float* __restrict__ x1, const float* __restrict__ x2,
    const float* __restrict__ w1, const float* __restrict__ b1,
    const float* __restrict__ w2, const float* __restrict__ b2,
    const float* __restrict__ w3, const float* __restrict__ b3,
    float* __restrict__ Q, float* __restrict__ K, float* __restrict__ V,
    float* __restrict__ out, float* __restrict__ dsum)
{
    if (blockIdx.x < 200)
        out[blockIdx.x * 256 + threadIdx.x] = 0.f;
    else if (blockIdx.x < 220)
        dsum[(blockIdx.x - 200) * 256 + threadIdx.x] = 0.f;

    int arr = blockIdx.x / 200;            // 0=Q, 1=K, 2=V
    int rem = blockIdx.x - arr * 200;
    int f   = rem / 20;
    int nbk = rem - f * 20;
    int n   = nbk * 256 + threadIdx.x;
    int t = n >> 10, p = n & 1023;

    const float* x    = (arr == 1) ? x2 : x1;
    const float* w    = (arr == 0) ? w1 : (arr == 1) ? w2 : w3;
    const float* bias = (arr == 0) ? b1 : (arr == 1) ? b2 : b3;
    float*       dst  = (arr == 0) ? Q  : (arr == 1) ? K  : V;

    const float* xp = x + t * (C_IN * 1024) + p;
    const float* wr = w + f * C_IN;

    float4 wv[16];
#pragma unroll
    for (int i = 0; i < 16; ++i) wv[i] = ((const float4*)wr)[i];

    float acc = 0.f;
#pragma unroll
    for (int i = 0; i < 16; ++i) {
        acc = fmaf(wv[i].x, xp[(4 * i + 0) * 1024], acc);
        acc = fmaf(wv[i].y, xp[(4 * i + 1) * 1024], acc);
        acc = fmaf(wv[i].z, xp[(4 * i + 2) * 1024], acc);
        acc = fmaf(wv[i].w, xp[(4 * i + 3) * 1024], acc);
    }
    dst[n * FP + f] = acc + bias[f];
}

// ---------------------------------------------------------------------------
// Kernel B: softmax denominators. Thread owns ONE m-column (K in 10 VGPRs).
// Q rows are read at wave-uniform addresses -> scalar-load path, no LDS,
// no syncs. Grid = 20 mTiles x NCHUNKS = 2560 blocks, 40 j-iters each.
// dsum atomics: N_TOK * NCHUNKS = 655K.
// ---------------------------------------------------------------------------
__global__ __launch_bounds__(256) void denom_kernel(
    const float* __restrict__ Q, const float* __restrict__ K,
    float* __restrict__ dsum, int nclen)
{
    int mTile = blockIdx.x % 20;
    int nc    = blockIdx.x / 20;
    int tid   = threadIdx.x;
    int m0 = mTile * 256 + tid;            // owns exactly one m

    float kk[10];
    {
        const float* kp = K + m0 * FP;
        float4 a = ((const float4*)kp)[0];
        float4 b = ((const float4*)kp)[1];
        float2 e = ((const float2*)kp)[4];
        kk[0]=a.x; kk[1]=a.y; kk[2]=a.z; kk[3]=a.w;
        kk[4]=b.x; kk[5]=b.y; kk[6]=b.z; kk[7]=b.w;
        kk[8]=e.x; kk[9]=e.y;
    }

    float d = 0.f;
    int n0 = nc * nclen;
#pragma unroll 2
    for (int j = 0; j < nclen; ++j) {
        // uniform address: no tid term -> scalar loads into SGPRs
        const float* qp = Q + (n0 + j) * FP;
        float4 qa = ((const float4*)qp)[0];
        float4 qb = ((const float4*)qp)[1];
        float2 qc = ((const float2*)qp)[4];
        float s0 = 0.f, s1 = 0.f;          // 2 chains: halve dep latency
        s0 = fmaf(qa.x, kk[0], s0);  s1 = fmaf(qb.y, kk[5], s1);
        s0 = fmaf(qa.y, kk[1], s0);  s1 = fmaf(qb.z, kk[6], s1);
        s0 = fmaf(qa.z, kk[2], s0);  s1 = fmaf(qb.w, kk[7], s1);
        s0 = fmaf(qa.w, kk[3], s0);  s1 = fmaf(qc.x, kk[8], s1);
        s0 = fmaf(qb.x, kk[4], s0);  s1 = fmaf(qc.y, kk[9], s1);
        d += __expf(fminf(s0 + s1, 60.f));
    }
    atomicAdd(&dsum[m0], d);
}

// ---------------------------------------------------------------------------
// Kernel D: main fused pass. Thread owns ONE row n (q[10]+acc[10] VGPRs).
// K/V rows + dsum[j] read at wave-uniform addresses -> scalar-load path,
// no LDS, no syncs. invw computed inline: iw = w0 * rcp(dsum[j]).
// Grid = 20 nTiles x MCHUNKS = 2560 blocks, 40 j-iters each.
// Out atomics: N_TOK * MCHUNKS * 10 = 6.55M (write-through, ~26 MB: not
// binding per R6). coef(n,m) = w0*relu(s) + w1*sigmoid(s) + exp(s)*invw[m]
// ---------------------------------------------------------------------------
__global__ __launch_bounds__(256) void main_kernel(
    const float* __restrict__ Q, const float* __restrict__ K,
    const float* __restrict__ V, const float* __restrict__ dsum,
    const float* __restrict__ aw, float* __restrict__ out, int mclen)
{
    int nTile = blockIdx.x % 20;
    int mc    = blockIdx.x / 20;
    int tid   = threadIdx.x;
    int nb = nTile * 256 + tid;            // owns exactly one row
    float w0 = aw[0], w1v = aw[1];

    float q[10];
    {
        const float* qp = Q + nb * FP;
        float4 a = ((const float4*)qp)[0];
        float4 b = ((const float4*)qp)[1];
        float2 e = ((const float2*)qp)[4];
        q[0]=a.x; q[1]=a.y; q[2]=a.z; q[3]=a.w;
        q[4]=b.x; q[5]=b.y; q[6]=b.z; q[7]=b.w;
        q[8]=e.x; q[9]=e.y;
    }

    float acc[F_OUT];
#pragma unroll
    for (int f = 0; f < F_OUT; ++f) acc[f] = 0.f;

    int m0 = mc * mclen;
#pragma unroll 2
    for (int j = 0; j < mclen; ++j) {
        // uniform addresses: no tid term -> scalar loads into SGPRs
        const float* kp = K + (m0 + j) * FP;
        float4 ka = ((const float4*)kp)[0];
        float4 kb = ((const float4*)kp)[1];
        float2 kc = ((const float2*)kp)[4];
        const float* vp = V + (m0 + j) * FP;
        float4 va = ((const float4*)vp)[0];
        float4 vb4 = ((const float4*)vp)[1];
        float2 vc = ((const float2*)vp)[4];
        float iw = w0 * __builtin_amdgcn_rcpf(dsum[m0 + j]);

        float s0 = 0.f, s1 = 0.f;          // 2 chains: halve dep latency
        s0 = fmaf(ka.x, q[0], s0);  s1 = fmaf(kb.y, q[5], s1);
        s0 = fmaf(ka.y, q[1], s0);  s1 = fmaf(kb.z, q[6], s1);
        s0 = fmaf(ka.z, q[2], s0);  s1 = fmaf(kb.w, q[7], s1);
        s0 = fmaf(ka.w, q[3], s0);  s1 = fmaf(kc.x, q[8], s1);
        s0 = fmaf(kb.x, q[4], s0);  s1 = fmaf(kc.y, q[9], s1);
        float s  = s0 + s1;
        float rl = fmaxf(s, 0.f);
        float e  = __expf(fminf(s, 60.f));
        float sg = e * __builtin_amdgcn_rcpf(1.f + e);
        float cf = fmaf(e, iw, fmaf(w1v, sg, w0 * rl));

        acc[0] = fmaf(cf, va.x,  acc[0]);
        acc[1] = fmaf(cf, va.y,  acc[1]);
        acc[2] = fmaf(cf, va.z,  acc[2]);
        acc[3] = fmaf(cf, va.w,  acc[3]);
        acc[4] = fmaf(cf, vb4.x, acc[4]);
        acc[5] = fmaf(cf, vb4.y, acc[5]);
        acc[6] = fmaf(cf, vb4.z, acc[6]);
        acc[7] = fmaf(cf, vb4.w, acc[7]);
        acc[8] = fmaf(cf, vc.x,  acc[8]);
        acc[9] = fmaf(cf, vc.y,  acc[9]);
    }

    // direct transposed accumulation into out[((t*10+f)<<10) + p]
    int t = nb >> 10, p = nb & 1023;
    float* obase = out + ((t * F_OUT) << 10) + p;
#pragma unroll
    for (int f = 0; f < F_OUT; ++f)
        atomicAdd(obase + (f << 10), acc[f]);
}

// ---------------------------------------------------------------------------
extern "C" void kernel_launch(void* const* d_in, const int* in_sizes, int n_in,
                              void* d_out, int out_size, void* d_ws, size_t ws_size,
                              hipStream_t stream)
{
    const float* in1 = (const float*)d_in[0];
    const float* in2 = (const float*)d_in[1];
    const float* aw  = (const float*)d_in[2];
    const float* w1  = (const float*)d_in[3];
    const float* b1  = (const float*)d_in[4];
    const float* w2  = (const float*)d_in[5];
    const float* b2  = (const float*)d_in[6];
    const float* w3  = (const float*)d_in[7];
    const float* b3  = (const float*)d_in[8];
    float* out = (float*)d_out;

    // workspace: Q/K/V padded rows + dsum (~758 KB)
    float* ws   = (float*)d_ws;
    float* Q    = ws;                        // N*FP
    float* K    = Q + N_TOK * FP;
    float* V    = K + N_TOK * FP;
    float* dsum = V + N_TOK * FP;            // N

    int nclen = N_TOK / NCHUNKS;   // 40
    int mclen = N_TOK / MCHUNKS;   // 40

    qkv_kernel<<<600, 256, 0, stream>>>(in1, in2, w1, b1, w2, b2, w3, b3,
                                        Q, K, V, out, dsum);
    denom_kernel<<<20 * NCHUNKS, 256, 0, stream>>>(Q, K, dsum, nclen);
    main_kernel<<<20 * MCHUNKS, 256, 0, stream>>>(Q, K, V, dsum, aw, out, mclen);
}

// Round 8
// 112.971 us; speedup vs baseline: 1.1319x; 1.1319x over previous
//
#include <hip/hip_runtime.h>

// Problem constants: B=1, T=5, C=64, H=W=32, F=10
#define N_TOK   5120      // T*H*W
#define C_IN    64
#define F_OUT   10
#define FP      12        // padded row stride in ws: [0..9]=data

#define DTILE   40        // denom: Q rows staged per LDS tile
#define MTILE   40        // main: K/V rows staged per LDS tile
#define NCHUNKS 128       // denom n-chunks  -> grid 20*128 = 2560 blocks
#define MCHUNKS 128       // main  m-chunks  -> grid 20*128 = 2560 blocks

// Session ledger: R4 grid-barrier = ~250us (stay multi-kernel). R6: atomic
// write-through traffic not binding. R7: no-LDS scalar loads regress (latency
// per j not amortizable) -> LDS staging is right, but R5-main was LDS-ISSUE-
// bound (6 ds_read_b128/j = 72cyc vs 54cyc VALU). R8: pack Q/K as f16 pairs,
// dot with v_dot2_f32_f16 -> main 4 reads/j, denom 2 reads/j.

typedef _Float16 h2 __attribute__((ext_vector_type(2)));

__device__ __forceinline__ uint pack2(float a, float b) {
    h2 h = { (_Float16)a, (_Float16)b };
    return __builtin_bit_cast(uint, h);
}
__device__ __forceinline__ h2    as_h2(uint u) { return __builtin_bit_cast(h2, u); }
__device__ __forceinline__ float as_f(uint u)  { return __builtin_bit_cast(float, u); }
__device__ __forceinline__ uint  as_u(float f) { return __builtin_bit_cast(uint, f); }

// ---------------------------------------------------------------------------
// Kernel A: q/k/v pointwise conv. Thread = one (n, f, arr) output value.
// 600 blocks: arr(3) x f(10) x nblk(20). 64 coalesced loads + 64 FMA each.
// Prologue: blocks [0,200) zero out (51200 f), blocks [200,220) zero dsum.
// ---------------------------------------------------------------------------
__global__ __launch_bounds__(256) void qkv_kernel(
    const float* __restrict__ x1, const float* __restrict__ x2,
    const float* __restrict__ w1, const float* __restrict__ b1,
    const float* __restrict__ w2, const float* __restrict__ b2,
    const float* __restrict__ w3, const float* __restrict__ b3,
    float* __restrict__ Q, float* __restrict__ K, float* __restrict__ V,
    float* __restrict__ out, float* __restrict__ dsum)
{
    if (blockIdx.x < 200)
        out[blockIdx.x * 256 + threadIdx.x] = 0.f;
    else if (blockIdx.x < 220)
        dsum[(blockIdx.x - 200) * 256 + threadIdx.x] = 0.f;

    int arr = blockIdx.x / 200;            // 0=Q, 1=K, 2=V
    int rem = blockIdx.x - arr * 200;
    int f   = rem / 20;
    int nbk = rem - f * 20;
    int n   = nbk * 256 + threadIdx.x;
    int t = n >> 10, p = n & 1023;

    const float* x    = (arr == 1) ? x2 : x1;
    const float* w    = (arr == 0) ? w1 : (arr == 1) ? w2 : w3;
    const float* bias = (arr == 0) ? b1 : (arr == 1) ? b2 : b3;
    float*       dst  = (arr == 0) ? Q  : (arr == 1) ? K  : V;

    const float* xp = x + t * (C_IN * 1024) + p;
    const float* wr = w + f * C_IN;

    float4 wv[16];
#pragma unroll
    for (int i = 0; i < 16; ++i) wv[i] = ((const float4*)wr)[i];

    float acc = 0.f;
#pragma unroll
    for (int i = 0; i < 16; ++i) {
        acc = fmaf(wv[i].x, xp[(4 * i + 0) * 1024], acc);
        acc = fmaf(wv[i].y, xp[(4 * i + 1) * 1024], acc);
        acc = fmaf(wv[i].z, xp[(4 * i + 2) * 1024], acc);
        acc = fmaf(wv[i].w, xp[(4 * i + 3) * 1024], acc);
    }
    dst[n * FP + f] = acc + bias[f];
}

// ---------------------------------------------------------------------------
// Kernel B: softmax denominators. Thread owns ONE m-column; K row packed to
// 5 h2 regs. Q rows staged in LDS as f16 pairs (5 dw + pad, stride 12 dw)
// -> 2 LDS reads per j (b128+b32, was 3xb128). QK dot = 5x v_dot2_f32_f16.
// Grid = 20 mTiles x NCHUNKS = 2560 blocks. dsum atomics: 655K.
// ---------------------------------------------------------------------------
__global__ __launch_bounds__(256) void denom_kernel(
    const float* __restrict__ Q, const float* __restrict__ K,
    float* __restrict__ dsum, int nclen)
{
    int mTile = blockIdx.x % 20;
    int nc    = blockIdx.x / 20;
    int tid   = threadIdx.x;
    int m0 = mTile * 256 + tid;            // owns exactly one m

    h2 kh[5];
    {
        const float* kp = K + m0 * FP;
        float4 a = ((const float4*)kp)[0];
        float4 b = ((const float4*)kp)[1];
        float2 e = ((const float2*)kp)[4];
        kh[0] = h2{ (_Float16)a.x, (_Float16)a.y };
        kh[1] = h2{ (_Float16)a.z, (_Float16)a.w };
        kh[2] = h2{ (_Float16)b.x, (_Float16)b.y };
        kh[3] = h2{ (_Float16)b.z, (_Float16)b.w };
        kh[4] = h2{ (_Float16)e.x, (_Float16)e.y };
    }

    __shared__ __align__(16) uint sq[DTILE * 12];   // packed Q rows, 1920 B

    float d = 0.f;
    int n0 = nc * nclen;
    for (int base = n0; base < n0 + nclen; base += DTILE) {
        __syncthreads();
        if (tid < DTILE) {                 // thread packs one Q row -> 5 dw
            const float* qp = Q + (base + tid) * FP;
            float4 a = ((const float4*)qp)[0];
            float4 b = ((const float4*)qp)[1];
            float2 e = ((const float2*)qp)[4];
            uint* dst = sq + tid * 12;
            ((uint4*)dst)[0] = make_uint4(pack2(a.x, a.y), pack2(a.z, a.w),
                                          pack2(b.x, b.y), pack2(b.z, b.w));
            dst[4] = pack2(e.x, e.y);
        }
        __syncthreads();
#pragma unroll 4
        for (int j = 0; j < DTILE; ++j) {
            uint4 A  = ((const uint4*)(sq + j * 12))[0];
            uint  a4 = sq[j * 12 + 4];
            float s = __builtin_amdgcn_fdot2(as_h2(A.x), kh[0], 0.f, false);
            s = __builtin_amdgcn_fdot2(as_h2(A.y), kh[1], s, false);
            s = __builtin_amdgcn_fdot2(as_h2(A.z), kh[2], s, false);
            s = __builtin_amdgcn_fdot2(as_h2(A.w), kh[3], s, false);
            s = __builtin_amdgcn_fdot2(as_h2(a4),  kh[4], s, false);
            d += __expf(fminf(s, 60.f));
        }
    }
    atomicAdd(&dsum[m0], d);
}

// ---------------------------------------------------------------------------
// Kernel D: main fused pass. Thread owns ONE row n; Q row packed to 5 h2
// regs. Per-j LDS record (stride 20 dw, 16 used): [0..4]=K f16-pairs,
// [5]=invw f32, [6..15]=V f32 -> 4x ds_read_b128 per j (was 6).
// QK dot = 5x v_dot2_f32_f16; V accumulate stays f32.
// Grid = 20 nTiles x MCHUNKS = 2560 blocks. Out atomics: 6.55M.
// coef(n,m) = w0*relu(s) + w1*sigmoid(s) + exp(s)*invw[m]
// ---------------------------------------------------------------------------
__global__ __launch_bounds__(256) void main_kernel(
    const float* __restrict__ Q, const float* __restrict__ K,
    const float* __restrict__ V, const float* __restrict__ dsum,
    const float* __restrict__ aw, float* __restrict__ out, int mclen)
{
    int nTile = blockIdx.x % 20;
    int mc    = blockIdx.x / 20;
    int tid   = threadIdx.x;
    int nb = nTile * 256 + tid;            // owns exactly one row
    float w0 = aw[0], w1v = aw[1];

    h2 qh[5];
    {
        const float* qp = Q + nb * FP;
        float4 a = ((const float4*)qp)[0];
        float4 b = ((const float4*)qp)[1];
        float2 e = ((const float2*)qp)[4];
        qh[0] = h2{ (_Float16)a.x, (_Float16)a.y };
        qh[1] = h2{ (_Float16)a.z, (_Float16)a.w };
        qh[2] = h2{ (_Float16)b.x, (_Float16)b.y };
        qh[3] = h2{ (_Float16)b.z, (_Float16)b.w };
        qh[4] = h2{ (_Float16)e.x, (_Float16)e.y };
    }

    float acc[F_OUT];
#pragma unroll
    for (int f = 0; f < F_OUT; ++f) acc[f] = 0.f;

    __shared__ __align__(16) uint sm[MTILE * 20];   // packed K/iw/V rows, 3200 B

    int mstart = mc * mclen;
    for (int mbase = mstart; mbase < mstart + mclen; mbase += MTILE) {
        __syncthreads();
        if (tid < MTILE) {                 // thread packs one K/V row -> 16 dw
            int m = mbase + tid;
            const float* kp = K + m * FP;
            float4 ka = ((const float4*)kp)[0];
            float4 kb = ((const float4*)kp)[1];
            float2 kc = ((const float2*)kp)[4];
            const float* vp = V + m * FP;
            float4 va = ((const float4*)vp)[0];
            float4 vb = ((const float4*)vp)[1];
            float2 vc = ((const float2*)vp)[4];
            float iw = w0 * __builtin_amdgcn_rcpf(dsum[m]);
            uint* dst = sm + tid * 20;
            ((uint4*)dst)[0] = make_uint4(pack2(ka.x, ka.y), pack2(ka.z, ka.w),
                                          pack2(kb.x, kb.y), pack2(kb.z, kb.w));
            ((uint4*)dst)[1] = make_uint4(pack2(kc.x, kc.y), as_u(iw),
                                          as_u(va.x), as_u(va.y));
            ((uint4*)dst)[2] = make_uint4(as_u(va.z), as_u(va.w),
                                          as_u(vb.x), as_u(vb.y));
            ((uint4*)dst)[3] = make_uint4(as_u(vb.z), as_u(vb.w),
                                          as_u(vc.x), as_u(vc.y));
        }
        __syncthreads();

#pragma unroll 4
        for (int j = 0; j < MTILE; ++j) {
            const uint4* rp = (const uint4*)(sm + j * 20);
            uint4 A = rp[0], B = rp[1], C = rp[2], D = rp[3];

            float s = __builtin_amdgcn_fdot2(qh[0], as_h2(A.x), 0.f, false);
            s = __builtin_amdgcn_fdot2(qh[1], as_h2(A.y), s, false);
            s = __builtin_amdgcn_fdot2(qh[2], as_h2(A.z), s, false);
            s = __builtin_amdgcn_fdot2(qh[3], as_h2(A.w), s, false);
            s = __builtin_amdgcn_fdot2(qh[4], as_h2(B.x), s, false);

            float iw = as_f(B.y);
            float rl = fmaxf(s, 0.f);
            float e  = __expf(fminf(s, 60.f));
            float sg = e * __builtin_amdgcn_rcpf(1.f + e);
            float cf = fmaf(e, iw, fmaf(w1v, sg, w0 * rl));

            acc[0] = fmaf(cf, as_f(B.z), acc[0]);
            acc[1] = fmaf(cf, as_f(B.w), acc[1]);
            acc[2] = fmaf(cf, as_f(C.x), acc[2]);
            acc[3] = fmaf(cf, as_f(C.y), acc[3]);
            acc[4] = fmaf(cf, as_f(C.z), acc[4]);
            acc[5] = fmaf(cf, as_f(C.w), acc[5]);
            acc[6] = fmaf(cf, as_f(D.x), acc[6]);
            acc[7] = fmaf(cf, as_f(D.y), acc[7]);
            acc[8] = fmaf(cf, as_f(D.z), acc[8]);
            acc[9] = fmaf(cf, as_f(D.w), acc[9]);
        }
    }

    // direct transposed accumulation into out[((t*10+f)<<10) + p]
    int t = nb >> 10, p = nb & 1023;
    float* obase = out + ((t * F_OUT) << 10) + p;
#pragma unroll
    for (int f = 0; f < F_OUT; ++f)
        atomicAdd(obase + (f << 10), acc[f]);
}

// ---------------------------------------------------------------------------
extern "C" void kernel_launch(void* const* d_in, const int* in_sizes, int n_in,
                              void* d_out, int out_size, void* d_ws, size_t ws_size,
                              hipStream_t stream)
{
    const float* in1 = (const float*)d_in[0];
    const float* in2 = (const float*)d_in[1];
    const float* aw  = (const float*)d_in[2];
    const float* w1  = (const float*)d_in[3];
    const float* b1  = (const float*)d_in[4];
    const float* w2  = (const float*)d_in[5];
    const float* b2  = (const float*)d_in[6];
    const float* w3  = (const float*)d_in[7];
    const float* b3  = (const float*)d_in[8];
    float* out = (float*)d_out;

    // workspace: Q/K/V padded rows + dsum (~758 KB)
    float* ws   = (float*)d_ws;
    float* Q    = ws;                        // N*FP
    float* K    = Q + N_TOK * FP;
    float* V    = K + N_TOK * FP;
    float* dsum = V + N_TOK * FP;            // N

    int nclen = N_TOK / NCHUNKS;   // 40 (single DTILE iter per block)
    int mclen = N_TOK / MCHUNKS;   // 40 (single MTILE iter per block)

    qkv_kernel<<<600, 256, 0, stream>>>(in1, in2, w1, b1, w2, b2, w3, b3,
                                        Q, K, V, out, dsum);
    denom_kernel<<<20 * NCHUNKS, 256, 0, stream>>>(Q, K, dsum, nclen);
    main_kernel<<<20 * MCHUNKS, 256, 0, stream>>>(Q, K, V, dsum, aw, out, mclen);
}